// Round 5
// baseline (353.723 us; speedup 1.0000x reference)
//
#include <hip/hip_runtime.h>

// MovingAvgNorm, R5: streaming running-window kernel. x (32,16384,80) fp32,
// k=100 reflect. Four rounds showed the LDS 3-phase structure pinned at
// 108-120us with NO pipe saturated (VALU<30%, HBM ~55% of achievable, LDS
// ~20%) -- barrier-serialized latency. Meanwhile fillBuffer in the same trace
// sustains 6.2 TB/s at 9.8% occupancy: streaming + deep MLP is all the
// memory system needs.
//
// Structure: thread = (batch, channel-pair, 128-step time chunk). Init: sum
// window rows [t0-50, t0+49] (100 loads, unroll 10). Stream: per step load
// center/enter/leave float2, emit output, update running s1/s2. No LDS, no
// barriers; unroll 8 keeps ~24 loads in flight per wave (~120KB/CU at 10
// waves/CU, 5x Little's law for 6.3 TB/s). Interior chunks (126/128) use a
// reflect-free pointer fast path. Nontemporal stores keep L2 for x.
// Coalescing: 40 lanes of a wave cover one contiguous 320B row (+24 lanes on
// the neighbor chunk's row) -> 2-3 segments per wave-load.
// Numerics: running sums drift <<1e-3 over 128 steps (threshold 0.1).

namespace {

constexpr int K    = 100;
constexpr int HALF = 50;
constexpr int Tn   = 16384;
constexpr int Bn   = 32;
constexpr int CPR  = 40;              // float2 per 80-float row
constexpr int CT   = 128;             // time steps per thread
constexpr int NQ   = Tn / CT;         // 128 chunks
constexpr int BLK  = 320;             // 5 waves/block
constexpr int NTH  = Bn * CPR * NQ;   // 163840 threads
constexpr int NBLK = NTH / BLK;       // 512 blocks = 2/CU exactly
constexpr float C1 = 1.0f / (float)K;
constexpr float C2 = 1.0f / (float)(K - 1);

__device__ __forceinline__ float fast_rsqrt(float v) {
#if __has_builtin(__builtin_amdgcn_rsqf)
  return __builtin_amdgcn_rsqf(v);
#else
  return __frsqrt_rn(v);
#endif
}

__device__ __forceinline__ int refl(int t) {
  t = (t < 0) ? -t : t;
  return (t >= Tn) ? 2 * (Tn - 1) - t : t;
}

__device__ __forceinline__ void nt_store_f2(float2* p, float2 o) {
  union { float2 f; double d; } u;
  u.f = o;
  __builtin_nontemporal_store(u.d, reinterpret_cast<double*>(p));
}

__global__ __launch_bounds__(BLK) void man_kernel(const float2* __restrict__ x,
                                                  float2* __restrict__ out) {
  const int n   = blockIdx.x * BLK + threadIdx.x;
  const int c2  = n % CPR;
  const int rem = n / CPR;
  const int q   = rem % NQ;
  const int b   = rem / NQ;
  const int t0  = q * CT;

  const float2* __restrict__ xb = x   + (size_t)b * Tn * CPR + c2;
  float2*       __restrict__ ob = out + (size_t)b * Tn * CPR + c2;

  float s1x = 0.f, s1y = 0.f, s2x = 0.f, s2y = 0.f;

  const bool interior = (t0 - HALF >= 0) && (t0 + CT - 1 + HALF < Tn);

  if (interior) {
    // ---- init: window [t0-50, t0+49], no reflection needed ----
    const float2* p = xb + (size_t)(t0 - HALF) * CPR;
#pragma unroll 10
    for (int j = 0; j < K; ++j) {
      float2 v = p[(size_t)j * CPR];
      s1x += v.x; s1y += v.y;
      s2x = fmaf(v.x, v.x, s2x);
      s2y = fmaf(v.y, v.y, s2y);
    }
    // ---- stream 128 outputs ----
    const float2* pc = xb + (size_t)t0 * CPR;
    const float2* pa = xb + (size_t)(t0 + HALF) * CPR;
    const float2* pr = xb + (size_t)(t0 - HALF) * CPR;
    float2*       po = ob + (size_t)t0 * CPR;
#pragma unroll 8
    for (int s = 0; s < CT; ++s) {
      float2 xc = pc[(size_t)s * CPR];
      float2 va = pa[(size_t)s * CPR];
      float2 vr = pr[(size_t)s * CPR];
      float mx = s1x * C1, my = s1y * C1;
      float vx = fmaf(-s1x, mx, s2x) * C2;
      float vy = fmaf(-s1y, my, s2y) * C2;
      float rx = fast_rsqrt(fmaxf(vx, 1e-30f));
      float ry = fast_rsqrt(fmaxf(vy, 1e-30f));
      nt_store_f2(po + (size_t)s * CPR,
                  make_float2((xc.x - mx) * rx, (xc.y - my) * ry));
      s1x += va.x - vr.x; s1y += va.y - vr.y;
      s2x = fmaf(va.x, va.x, s2x); s2x = fmaf(-vr.x, vr.x, s2x);
      s2y = fmaf(va.y, va.y, s2y); s2y = fmaf(-vr.y, vr.y, s2y);
    }
  } else {
    // ---- boundary chunks (q==0 or q==NQ-1): branchless reflect ----
#pragma unroll 10
    for (int j = 0; j < K; ++j) {
      int gr = refl(t0 - HALF + j);
      float2 v = xb[(size_t)gr * CPR];
      s1x += v.x; s1y += v.y;
      s2x = fmaf(v.x, v.x, s2x);
      s2y = fmaf(v.y, v.y, s2y);
    }
#pragma unroll 4
    for (int s = 0; s < CT; ++s) {
      int t = t0 + s;
      float2 xc = xb[(size_t)t * CPR];
      float2 va = xb[(size_t)refl(t + HALF) * CPR];
      float2 vr = xb[(size_t)refl(t - HALF) * CPR];
      float mx = s1x * C1, my = s1y * C1;
      float vx = fmaf(-s1x, mx, s2x) * C2;
      float vy = fmaf(-s1y, my, s2y) * C2;
      float rx = fast_rsqrt(fmaxf(vx, 1e-30f));
      float ry = fast_rsqrt(fmaxf(vy, 1e-30f));
      nt_store_f2(ob + (size_t)t * CPR,
                  make_float2((xc.x - mx) * rx, (xc.y - my) * ry));
      s1x += va.x - vr.x; s1y += va.y - vr.y;
      s2x = fmaf(va.x, va.x, s2x); s2x = fmaf(-vr.x, vr.x, s2x);
      s2y = fmaf(va.y, va.y, s2y); s2y = fmaf(-vr.y, vr.y, s2y);
    }
  }
}

}  // namespace

extern "C" void kernel_launch(void* const* d_in, const int* in_sizes, int n_in,
                              void* d_out, int out_size, void* d_ws, size_t ws_size,
                              hipStream_t stream) {
  (void)in_sizes; (void)n_in; (void)out_size; (void)d_ws; (void)ws_size;
  const float2* x = (const float2*)d_in[0];
  float2* o = (float2*)d_out;
  man_kernel<<<NBLK, BLK, 0, stream>>>(x, o);
}